// Round 1
// baseline (835.503 us; speedup 1.0000x reference)
//
#include <hip/hip_runtime.h>
#include <stdint.h>

typedef __attribute__((ext_vector_type(8))) short short8;
typedef __attribute__((ext_vector_type(4))) float f32x4;

#define B_ 2
#define H_ 16
#define S_ 2048
#define D_ 64

__device__ __forceinline__ short f2b(float f) {
  // fp32 -> bf16 bits, round-to-nearest-even
  unsigned u = __builtin_bit_cast(unsigned, f);
  u += 0x7fffu + ((u >> 16) & 1u);
  return (short)(u >> 16);
}

__global__ __launch_bounds__(256, 4)
void attn_kernel(const float* __restrict__ Q, const float* __restrict__ K,
                 const float* __restrict__ V, const int* __restrict__ M,
                 float* __restrict__ O, float* __restrict__ A)
{
  const int qt   = blockIdx.x;   // 0..31 q-tile of 64 rows
  const int bh   = blockIdx.y;   // 0..31 (b*H + h)
  const int b    = bh >> 4;
  const int tid  = threadIdx.x;
  const int wave = tid >> 6;
  const int lane = tid & 63;
  const int l15  = lane & 15;
  const int quad = lane >> 4;

  const float* Qp = Q + (size_t)bh * S_ * D_;
  const float* Kp = K + (size_t)bh * S_ * D_;
  const float* Vp = V + (size_t)bh * S_ * D_;
  const int*   Mp = M + (size_t)b * S_ * S_;
  float* Op = O + (size_t)bh * S_ * D_;
  float* Ap = A + (size_t)bh * S_ * S_;

  const int q0 = qt * 64 + wave * 16;   // this wave's 16 q-rows

  // LDS: K tile [kk][d] pad 72 (breaks 128B-stride bank aliasing on b128 reads),
  // V^T tile [d][kk] pad 40 (2-way, free), per-wave P tile pad 40.
  __shared__ __attribute__((aligned(16))) short Ks[32][72];
  __shared__ __attribute__((aligned(16))) short Vt[64][40];
  __shared__ __attribute__((aligned(16))) short Ps[4][16][40];

  // Q A-fragments (m=lane&15, k=quad*8+j), pre-scaled by 1/sqrt(D)=0.125
  short8 aq[2];
  {
    const float* qr = Qp + (size_t)(q0 + l15) * D_ + quad * 8;
#pragma unroll
    for (int h = 0; h < 2; ++h) {
      const float4 x0 = *(const float4*)(qr + h * 32);
      const float4 x1 = *(const float4*)(qr + h * 32 + 4);
      aq[h][0] = f2b(x0.x * 0.125f); aq[h][1] = f2b(x0.y * 0.125f);
      aq[h][2] = f2b(x0.z * 0.125f); aq[h][3] = f2b(x0.w * 0.125f);
      aq[h][4] = f2b(x1.x * 0.125f); aq[h][5] = f2b(x1.y * 0.125f);
      aq[h][6] = f2b(x1.z * 0.125f); aq[h][7] = f2b(x1.w * 0.125f);
    }
  }

  const int srow = tid >> 3;       // staging row 0..31
  const int sdc  = (tid & 7) * 8;  // staging d-chunk 0..56

  // ---------------- pass 1: masked row sums l ----------------
  float lsum[4] = {0.f, 0.f, 0.f, 0.f};
  for (int kt = 0; kt < S_; kt += 32) {
    __syncthreads();
    {
      const float* kr = Kp + (size_t)(kt + srow) * D_ + sdc;
      const float4 x0 = *(const float4*)(kr);
      const float4 x1 = *(const float4*)(kr + 4);
      short8 t;
      t[0]=f2b(x0.x); t[1]=f2b(x0.y); t[2]=f2b(x0.z); t[3]=f2b(x0.w);
      t[4]=f2b(x1.x); t[5]=f2b(x1.y); t[6]=f2b(x1.z); t[7]=f2b(x1.w);
      *(short8*)&Ks[srow][sdc] = t;
    }
    __syncthreads();

    f32x4 acc[2] = {{0.f,0.f,0.f,0.f},{0.f,0.f,0.f,0.f}};
#pragma unroll
    for (int nt = 0; nt < 2; ++nt)
#pragma unroll
      for (int h = 0; h < 2; ++h) {
        const short8 bk = *(const short8*)&Ks[nt*16 + l15][h*32 + quad*8];
        acc[nt] = __builtin_amdgcn_mfma_f32_16x16x32_bf16(aq[h], bk, acc[nt], 0, 0, 0);
      }
#pragma unroll
    for (int nt = 0; nt < 2; ++nt)
#pragma unroll
      for (int r = 0; r < 4; ++r) {
        const int row = q0 + quad*4 + r;          // C/D: row = quad*4+reg
        const int col = kt + nt*16 + l15;         // C/D: col = lane&15
        const int m = Mp[(size_t)row * S_ + col];
        lsum[r] += m ? __expf(acc[nt][r]) : 0.f;
      }
  }
  // reduce across the 16 col-lanes of each quad group; keep reciprocal
#pragma unroll
  for (int r = 0; r < 4; ++r) {
    float s = lsum[r];
    s += __shfl_xor(s, 1);
    s += __shfl_xor(s, 2);
    s += __shfl_xor(s, 4);
    s += __shfl_xor(s, 8);
    lsum[r] = (s > 0.f) ? (1.f / s) : 0.f;
  }

  // ---------------- pass 2: attn write + PV ----------------
  f32x4 oacc[4] = {{0.f,0.f,0.f,0.f},{0.f,0.f,0.f,0.f},
                   {0.f,0.f,0.f,0.f},{0.f,0.f,0.f,0.f}};

  for (int kt = 0; kt < S_; kt += 32) {
    __syncthreads();
    {
      const float* kr = Kp + (size_t)(kt + srow) * D_ + sdc;
      const float4 x0 = *(const float4*)(kr);
      const float4 x1 = *(const float4*)(kr + 4);
      short8 t;
      t[0]=f2b(x0.x); t[1]=f2b(x0.y); t[2]=f2b(x0.z); t[3]=f2b(x0.w);
      t[4]=f2b(x1.x); t[5]=f2b(x1.y); t[6]=f2b(x1.z); t[7]=f2b(x1.w);
      *(short8*)&Ks[srow][sdc] = t;

      const float* vr = Vp + (size_t)(kt + srow) * D_ + sdc;
      const float4 y0 = *(const float4*)(vr);
      const float4 y1 = *(const float4*)(vr + 4);
      Vt[sdc + 0][srow] = f2b(y0.x);
      Vt[sdc + 1][srow] = f2b(y0.y);
      Vt[sdc + 2][srow] = f2b(y0.z);
      Vt[sdc + 3][srow] = f2b(y0.w);
      Vt[sdc + 4][srow] = f2b(y1.x);
      Vt[sdc + 5][srow] = f2b(y1.y);
      Vt[sdc + 6][srow] = f2b(y1.z);
      Vt[sdc + 7][srow] = f2b(y1.w);
    }
    __syncthreads();

    f32x4 acc[2] = {{0.f,0.f,0.f,0.f},{0.f,0.f,0.f,0.f}};
#pragma unroll
    for (int nt = 0; nt < 2; ++nt)
#pragma unroll
      for (int h = 0; h < 2; ++h) {
        const short8 bk = *(const short8*)&Ks[nt*16 + l15][h*32 + quad*8];
        acc[nt] = __builtin_amdgcn_mfma_f32_16x16x32_bf16(aq[h], bk, acc[nt], 0, 0, 0);
      }

    // p = exp(s)*mask/l ; write attn ; stage P (C/D layout -> LDS)
#pragma unroll
    for (int nt = 0; nt < 2; ++nt)
#pragma unroll
      for (int r = 0; r < 4; ++r) {
        const int row = q0 + quad*4 + r;
        const int col = kt + nt*16 + l15;
        const int m = Mp[(size_t)row * S_ + col];
        const float p = m ? __expf(acc[nt][r]) * lsum[r] : 0.f;
        Ap[(size_t)row * S_ + col] = p;
        Ps[wave][quad*4 + r][nt*16 + l15] = f2b(p);
      }
    // own-wave LDS RAW: drain ds_writes before A-frag read (no barrier needed,
    // Ps is wave-private)
    __asm__ volatile("s_waitcnt lgkmcnt(0)" ::: "memory");

    const short8 ap = *(const short8*)&Ps[wave][l15][quad*8];  // A: m=lane&15,k=quad*8+j
#pragma unroll
    for (int nt = 0; nt < 4; ++nt) {
      const short8 bv = *(const short8*)&Vt[nt*16 + l15][quad*8]; // B: k=quad*8+j,n=lane&15
      oacc[nt] = __builtin_amdgcn_mfma_f32_16x16x32_bf16(ap, bv, oacc[nt], 0, 0, 0);
    }
  }

  // epilogue: out tile, C/D layout, coalesced in 16-lane groups
#pragma unroll
  for (int nt = 0; nt < 4; ++nt)
#pragma unroll
    for (int r = 0; r < 4; ++r)
      Op[(size_t)(q0 + quad*4 + r) * D_ + nt*16 + l15] = oacc[nt][r];
}

extern "C" void kernel_launch(void* const* d_in, const int* in_sizes, int n_in,
                              void* d_out, int out_size, void* d_ws, size_t ws_size,
                              hipStream_t stream) {
  const float* q = (const float*)d_in[0];
  const float* k = (const float*)d_in[1];
  const float* v = (const float*)d_in[2];
  const int*   m = (const int*)d_in[3];
  float* out  = (float*)d_out;
  float* attn = out + (size_t)B_ * H_ * S_ * D_;   // tuple order: (out, attn)

  dim3 grid(S_ / 64, B_ * H_);
  attn_kernel<<<grid, 256, 0, stream>>>(q, k, v, m, out, attn);
}